// Round 2
// baseline (1374.096 us; speedup 1.0000x reference)
//
#include <hip/hip_runtime.h>
#include <hip/hip_bf16.h>
#include <stdint.h>

#define NN 200000
#define DD 128

typedef __attribute__((ext_vector_type(8))) short short8;
typedef __attribute__((ext_vector_type(4))) float floatx4;

#define MFMA16(a,b,c) __builtin_amdgcn_mfma_f32_16x16x32_bf16(a,b,c,0,0,0)

// ---- workspace layout (bytes) ----
static constexpr size_t WS_SUM    = 0;          // 128 f32
static constexpr size_t WS_SQ     = 512;        // 128 f32
static constexpr size_t WS_FLAG   = 1024;       // u32 (1 = mask is 1-byte bools)
static constexpr size_t WS_HIST   = 1088;       // 13 u32 degree histogram
static constexpr size_t WS_OFF    = 1216;       // 13 u32 bucket offsets
static constexpr size_t WS_WHH    = 4096;       // 49152 u16, chunked frag layout
static constexpr size_t WS_WIH    = 102400;     // 49152 u16
static constexpr size_t WS_WSELF  = 200704;     // 16384 u16
static constexpr size_t WS_WNEIGH = 233472;     // 16384 u16
static constexpr size_t WS_DEG    = 266240;     // N u8
static constexpr size_t WS_PERM   = 466240;     // N i32
static constexpr size_t WS_XB     = 1266240;    // N*128 u16 (bf16 x)
static constexpr size_t WS_GI     = 52466240;   // N*384 u16 (bf16 gi)
// end = 206,066,240 bytes

__device__ __forceinline__ uint16_t f2b(float f){
    uint32_t u = __builtin_bit_cast(uint32_t, f);
    uint32_t r = u + 0x7FFFu + ((u >> 16) & 1u);
    return (uint16_t)(r >> 16);
}
__device__ __forceinline__ float b2f(uint16_t h){
    uint32_t u = ((uint32_t)h) << 16;
    return __builtin_bit_cast(float, u);
}
__device__ __forceinline__ float sigm(float x){
    float e = __builtin_amdgcn_exp2f(x * -1.4426950408889634f);
    return __builtin_amdgcn_rcpf(1.0f + e);
}
__device__ __forceinline__ float tanh_(float x){
    float e = __builtin_amdgcn_exp2f(x * 2.8853900817779268f); // e^{2x}
    return 1.0f - 2.0f * __builtin_amdgcn_rcpf(1.0f + e);
}

// ---- K0: zero BN accumulators + hist ----
__global__ void k_init(float* __restrict__ ws){
    ws[threadIdx.x] = 0.0f;
    ws[threadIdx.x + 256] = 0.0f;   // covers sum[128], sq[128], flag, hist, off
}

// ---- K1: detect mask element size (1-byte bool vs int32) ----
__global__ void k_detect(const uint32_t* __restrict__ mask_w, uint32_t* __restrict__ flag){
    __shared__ uint32_t any;
    if (threadIdx.x == 0) any = 0;
    __syncthreads();
    uint32_t loc = 0;
    for (int i = threadIdx.x; i < 4096; i += 256) loc |= (mask_w[i] & 0xFFFFFF00u);
    if (loc) atomicOr(&any, 1u);
    __syncthreads();
    if (threadIdx.x == 0) *flag = (any != 0) ? 1u : 0u;
}

// ---- K2: BN column stats ----
__global__ void k_stats(const float* __restrict__ feat, float* __restrict__ wsum, float* __restrict__ wsq){
    __shared__ float ssum[256], ssq[256];
    const int col = threadIdx.x & 127, half = threadIdx.x >> 7;
    float s = 0.f, q = 0.f;
    for (int r = blockIdx.x * 2 + half; r < NN; r += gridDim.x * 2){
        float v = feat[(size_t)r * DD + col];
        s += v; q += v * v;
    }
    ssum[threadIdx.x] = s; ssq[threadIdx.x] = q;
    __syncthreads();
    if (threadIdx.x < 128){
        atomicAdd(&wsum[col], ssum[threadIdx.x] + ssum[threadIdx.x + 128]);
        atomicAdd(&wsq[col],  ssq[threadIdx.x]  + ssq[threadIdx.x + 128]);
    }
}

// ---- K3: weights -> bf16 in MFMA-B-fragment-chunked layout ----
__global__ void k_prep(const float* __restrict__ Wih, const float* __restrict__ Whh,
                       const float* __restrict__ Wself, const float* __restrict__ Wneigh,
                       uint16_t* __restrict__ whh_c, uint16_t* __restrict__ wih_c,
                       uint16_t* __restrict__ wself_c, uint16_t* __restrict__ wneigh_c){
    int i = blockIdx.x * 256 + threadIdx.x;
    if (i < 49152){
        int j = i & 7, cidx = i >> 3, n = cidx % 384, kq = cidx / 384;
        whh_c[i] = f2b(Whh[n * 128 + kq * 8 + j]);
    } else if (i < 98304){
        int e = i - 49152;
        int j = e & 7, cidx = e >> 3, n = cidx % 384, kq = cidx / 384;
        wih_c[e] = f2b(Wih[n * 128 + kq * 8 + j]);
    } else if (i < 114688){
        int e = i - 98304;
        int j = e & 7, cidx = e >> 3, n = cidx & 127, kq = cidx >> 7;
        wself_c[e] = f2b(Wself[n * 128 + kq * 8 + j]);
    } else {
        int e = i - 114688;
        int j = e & 7, cidx = e >> 3, n = cidx & 127, kq = cidx >> 7;
        wneigh_c[e] = f2b(Wneigh[n * 128 + kq * 8 + j]);
    }
}

// ---- K4: per-node degree + histogram ----
__global__ void k_hist(const void* __restrict__ mask, const uint32_t* __restrict__ flag,
                       uint8_t* __restrict__ deg, uint32_t* __restrict__ hist){
    int n = blockIdx.x * 256 + threadIdx.x;
    if (n >= NN) return;
    const uint32_t flg = *flag;
    int d = 0;
    if (flg){
        const uint8_t* m = (const uint8_t*)mask + (size_t)n * 12;
        for (int t = 0; t < 12; t++) d += m[t] ? 1 : 0;
    } else {
        const int* m = (const int*)mask + (size_t)n * 12;
        for (int t = 0; t < 12; t++) d += m[t] ? 1 : 0;
    }
    deg[n] = (uint8_t)d;
    atomicAdd(&hist[d], 1u);
}

// ---- K5: bucket offsets (descending degree) ----
__global__ void k_scan(const uint32_t* __restrict__ hist, uint32_t* __restrict__ off){
    if (threadIdx.x == 0){
        uint32_t acc = 0;
        for (int d = 12; d >= 0; d--){ off[d] = acc; acc += hist[d]; }
    }
}

// ---- K6: scatter node ids into perm, block-aggregated atomics ----
__global__ void k_scatter(const uint8_t* __restrict__ deg, uint32_t* __restrict__ off,
                          int* __restrict__ perm){
    __shared__ uint32_t lh[13], basebuf[13];
    if (threadIdx.x < 13) lh[threadIdx.x] = 0;
    __syncthreads();
    int n = blockIdx.x * 256 + threadIdx.x;
    int d = 0; uint32_t r = 0;
    bool valid = n < NN;
    if (valid){ d = deg[n]; r = atomicAdd(&lh[d], 1u); }
    __syncthreads();
    if (threadIdx.x < 13 && lh[threadIdx.x]) basebuf[threadIdx.x] = atomicAdd(&off[threadIdx.x], lh[threadIdx.x]);
    __syncthreads();
    if (valid) perm[basebuf[d] + r] = n;
}

// ---- K7: BN apply -> x bf16 ----
__global__ void k_bn(const float* __restrict__ feat, const float* __restrict__ gamma,
                     const float* __restrict__ beta, const float* __restrict__ wsum,
                     const float* __restrict__ wsq, uint16_t* __restrict__ xb){
    const int col = threadIdx.x & 127;
    const int strideRows = (gridDim.x * blockDim.x) >> 7;
    const int row0 = (blockIdx.x * blockDim.x + threadIdx.x) >> 7;
    float mu  = wsum[col] * (1.0f / NN);
    float var = wsq[col] * (1.0f / NN) - mu * mu;
    float rs  = rsqrtf(var + 1e-5f);
    float g = gamma[col] * rs;
    float b = beta[col] - mu * g;
    for (int r = row0; r < NN; r += strideRows)
        xb[(size_t)r * DD + col] = f2b(feat[(size_t)r * DD + col] * g + b);
}

// ---- K8: gi = x @ W_ih^T + b_ih  (64 rows per wave, B reused 4x) ----
__global__ __launch_bounds__(256) void k_gi(const uint16_t* __restrict__ xb,
                                            const uint16_t* __restrict__ wih_c,
                                            const float* __restrict__ b_ih,
                                            uint16_t* __restrict__ gi){
    const int tid = threadIdx.x, lane = tid & 63, w = tid >> 6, q = lane >> 4, c = lane & 15;
    const int wrow = (blockIdx.x * 4 + w) * 64;
    if (wrow >= NN) return;
    short8 A[4][4];
#pragma unroll
    for (int m = 0; m < 4; m++)
#pragma unroll
        for (int kb = 0; kb < 4; kb++)
            A[m][kb] = *(const short8*)(xb + (size_t)(wrow + m * 16 + c) * 128 + kb * 32 + q * 8);
#pragma unroll
    for (int nb = 0; nb < 24; nb++){
        floatx4 acc[4];
#pragma unroll
        for (int m = 0; m < 4; m++) acc[m] = floatx4{0.f, 0.f, 0.f, 0.f};
#pragma unroll
        for (int kb = 0; kb < 4; kb++){
            short8 B = *(const short8*)(wih_c + ((size_t)(kb * 4 + q) * 384 + nb * 16 + c) * 8);
#pragma unroll
            for (int m = 0; m < 4; m++) acc[m] = MFMA16(A[m][kb], B, acc[m]);
        }
        int colg = nb * 16 + c;
        float bias = b_ih[colg];
#pragma unroll
        for (int m = 0; m < 4; m++)
#pragma unroll
            for (int j = 0; j < 4; j++){
                int row = wrow + m * 16 + q * 4 + j;
                gi[(size_t)row * 384 + colg] = f2b(acc[m][j] + bias);
            }
    }
}

// ---- K9: GRU scan (degree-sorted) + final projections ----
__global__ __launch_bounds__(256, 1) void k_gru(
    const uint16_t* __restrict__ xb, const uint16_t* __restrict__ gi,
    const uint16_t* __restrict__ whh_c, const uint16_t* __restrict__ wself_c,
    const uint16_t* __restrict__ wneigh_c, const float* __restrict__ b_hh,
    const int* __restrict__ src_idx, const void* __restrict__ mask,
    const uint32_t* __restrict__ flag, const int* __restrict__ perm,
    const uint8_t* __restrict__ degp, float* __restrict__ out)
{
    __shared__ __align__(16) uint16_t hbuf[2][64][136];
    __shared__ int src_s[768];
    __shared__ uint8_t mask_s[768];
    __shared__ int perm_s[64];
    __shared__ int tmax_s;

    const int tid = threadIdx.x, lane = tid & 63, w = tid >> 6, q = lane >> 4, c = lane & 15;
    const int base = blockIdx.x * 64;

    if (tid < 64) perm_s[tid] = perm[base + tid];
    if (tid == 0) tmax_s = 0;
    __syncthreads();

    const uint32_t flg = *flag;
    for (int i = tid; i < 768; i += 256){
        int node = perm_s[i / 12];
        size_t offn = (size_t)node * 12 + (i % 12);
        src_s[i] = src_idx[offn];
        uint8_t mv;
        if (flg) mv = ((const uint8_t*)mask)[offn] ? 1 : 0;
        else     mv = ((const int*)mask)[offn] ? 1 : 0;
        mask_s[i] = mv;
    }
    if (tid < 64) atomicMax(&tmax_s, (int)degp[perm_s[tid]]);
    for (int i = tid; i < 64 * 136 / 2; i += 256) ((uint32_t*)hbuf[0])[i] = 0;

    // persistent W_hh B fragments (96 VGPRs) + biases
    short8 Bh[3][2][4];
    float bhh[3][2];
#pragma unroll
    for (int g = 0; g < 3; g++)
#pragma unroll
        for (int p = 0; p < 2; p++){
            int n = g * 128 + w * 32 + p * 16 + c;
            bhh[g][p] = b_hh[n];
#pragma unroll
            for (int kb = 0; kb < 4; kb++)
                Bh[g][p][kb] = *(const short8*)(whh_c + ((size_t)(kb * 4 + q) * 384 + n) * 8);
        }

    float hC[4][2][4];
#pragma unroll
    for (int m = 0; m < 4; m++)
#pragma unroll
        for (int p = 0; p < 2; p++)
#pragma unroll
            for (int j = 0; j < 4; j++) hC[m][p][j] = 0.f;

    __syncthreads();
    const int tmax = tmax_s;

    for (int t = 0; t < tmax; t++){
        const int rb = t & 1, wbuf = rb ^ 1;
        // gather gi for this step: 1 base addr per (m,j), 6 imm-offset loads
        uint16_t gv[4][3][2][4];
        uint8_t  mk[4][4];
#pragma unroll
        for (int m = 0; m < 4; m++)
#pragma unroll
            for (int j = 0; j < 4; j++){
                int row = m * 16 + q * 4 + j;
                int s = src_s[row * 12 + t];
                mk[m][j] = mask_s[row * 12 + t];
                const uint16_t* a = gi + (size_t)s * 384 + w * 32 + c;
                gv[m][0][0][j] = a[0];   gv[m][0][1][j] = a[16];
                gv[m][1][0][j] = a[128]; gv[m][1][1][j] = a[144];
                gv[m][2][0][j] = a[256]; gv[m][2][1][j] = a[272];
            }
#pragma unroll
        for (int m = 0; m < 4; m++){
            short8 A[4];
#pragma unroll
            for (int kb = 0; kb < 4; kb++)
                A[kb] = *(const short8*)&hbuf[rb][m * 16 + c][kb * 32 + q * 8];
            floatx4 acc[3][2];
#pragma unroll
            for (int g = 0; g < 3; g++)
#pragma unroll
                for (int p = 0; p < 2; p++){
                    floatx4 a0 = {0.f, 0.f, 0.f, 0.f};
#pragma unroll
                    for (int kb = 0; kb < 4; kb++) a0 = MFMA16(A[kb], Bh[g][p][kb], a0);
                    acc[g][p] = a0;
                }
#pragma unroll
            for (int p = 0; p < 2; p++)
#pragma unroll
                for (int j = 0; j < 4; j++){
                    float grv = b2f(gv[m][0][p][j]) + acc[0][p][j] + bhh[0][p];
                    float gzv = b2f(gv[m][1][p][j]) + acc[1][p][j] + bhh[1][p];
                    float hn  = acc[2][p][j] + bhh[2][p];
                    float r = sigm(grv);
                    float z = sigm(gzv);
                    float nn = tanh_(b2f(gv[m][2][p][j]) + r * hn);
                    float hold = hC[m][p][j];
                    float hnew = nn + z * (hold - nn);
                    hnew = mk[m][j] ? hnew : hold;
                    hC[m][p][j] = hnew;
                    hbuf[wbuf][m * 16 + q * 4 + j][w * 32 + p * 16 + c] = f2b(hnew);
                }
        }
        __syncthreads();
    }

    const int fb = tmax & 1;   // final h buffer

    // epilogue: out = x @ W_self^T + h @ W_neigh^T
    floatx4 acc2[4][2];
#pragma unroll
    for (int m = 0; m < 4; m++)
#pragma unroll
        for (int p = 0; p < 2; p++) acc2[m][p] = floatx4{0.f, 0.f, 0.f, 0.f};
#pragma unroll
    for (int m = 0; m < 4; m++){
        short8 A[4];
#pragma unroll
        for (int kb = 0; kb < 4; kb++)
            A[kb] = *(const short8*)&hbuf[fb][m * 16 + c][kb * 32 + q * 8];
#pragma unroll
        for (int p = 0; p < 2; p++)
#pragma unroll
            for (int kb = 0; kb < 4; kb++){
                short8 B = *(const short8*)(wneigh_c + ((size_t)(kb * 4 + q) * 128 + w * 32 + p * 16 + c) * 8);
                acc2[m][p] = MFMA16(A[kb], B, acc2[m][p]);
            }
    }
#pragma unroll
    for (int m = 0; m < 4; m++){
        int xrow = perm_s[m * 16 + c];
        short8 A[4];
#pragma unroll
        for (int kb = 0; kb < 4; kb++)
            A[kb] = *(const short8*)(xb + (size_t)xrow * 128 + kb * 32 + q * 8);
#pragma unroll
        for (int p = 0; p < 2; p++)
#pragma unroll
            for (int kb = 0; kb < 4; kb++){
                short8 B = *(const short8*)(wself_c + ((size_t)(kb * 4 + q) * 128 + w * 32 + p * 16 + c) * 8);
                acc2[m][p] = MFMA16(A[kb], B, acc2[m][p]);
            }
    }
#pragma unroll
    for (int m = 0; m < 4; m++){
#pragma unroll
        for (int j = 0; j < 4; j++){
            int orow = perm_s[m * 16 + q * 4 + j];
#pragma unroll
            for (int p = 0; p < 2; p++)
                out[(size_t)orow * 128 + w * 32 + p * 16 + c] = acc2[m][p][j];
        }
    }
}

extern "C" void kernel_launch(void* const* d_in, const int* in_sizes, int n_in,
                              void* d_out, int out_size, void* d_ws, size_t ws_size,
                              hipStream_t stream) {
    const float* feat    = (const float*)d_in[0];
    const float* gamma   = (const float*)d_in[1];
    const float* beta    = (const float*)d_in[2];
    const float* W_ih    = (const float*)d_in[3];
    const float* W_hh    = (const float*)d_in[4];
    const float* b_ih    = (const float*)d_in[5];
    const float* b_hh    = (const float*)d_in[6];
    const float* W_self  = (const float*)d_in[7];
    const float* W_neigh = (const float*)d_in[8];
    const int*   src_idx = (const int*)d_in[9];
    const void*  mask    = (const void*)d_in[10];
    float* out = (float*)d_out;

    char* ws = (char*)d_ws;
    float*    wsum     = (float*)(ws + WS_SUM);
    float*    wsq      = (float*)(ws + WS_SQ);
    uint32_t* flag     = (uint32_t*)(ws + WS_FLAG);
    uint32_t* hist     = (uint32_t*)(ws + WS_HIST);
    uint32_t* off      = (uint32_t*)(ws + WS_OFF);
    uint16_t* whh_c    = (uint16_t*)(ws + WS_WHH);
    uint16_t* wih_c    = (uint16_t*)(ws + WS_WIH);
    uint16_t* wself_c  = (uint16_t*)(ws + WS_WSELF);
    uint16_t* wneigh_c = (uint16_t*)(ws + WS_WNEIGH);
    uint8_t*  deg      = (uint8_t*)(ws + WS_DEG);
    int*      perm     = (int*)(ws + WS_PERM);
    uint16_t* xb       = (uint16_t*)(ws + WS_XB);
    uint16_t* gi       = (uint16_t*)(ws + WS_GI);

    k_init   <<<1,    256, 0, stream>>>((float*)ws);
    k_detect <<<1,    256, 0, stream>>>((const uint32_t*)mask, flag);
    k_stats  <<<512,  256, 0, stream>>>(feat, wsum, wsq);
    k_prep   <<<512,  256, 0, stream>>>(W_ih, W_hh, W_self, W_neigh, whh_c, wih_c, wself_c, wneigh_c);
    k_hist   <<<782,  256, 0, stream>>>(mask, flag, deg, hist);
    k_scan   <<<1,    64,  0, stream>>>(hist, off);
    k_scatter<<<782,  256, 0, stream>>>(deg, off, perm);
    k_bn     <<<782,  256, 0, stream>>>(feat, gamma, beta, wsum, wsq, xb);
    k_gi     <<<782,  256, 0, stream>>>(xb, wih_c, b_ih, gi);
    k_gru    <<<3125, 256, 0, stream>>>(xb, gi, whh_c, wself_c, wneigh_c, b_hh, src_idx, mask, flag, perm, deg, out);
}

// Round 3
// 775.800 us; speedup vs baseline: 1.7712x; 1.7712x over previous
//
#include <hip/hip_runtime.h>
#include <hip/hip_bf16.h>
#include <stdint.h>

#define NN 200000
#define DD 128

typedef __attribute__((ext_vector_type(8))) short short8;
typedef __attribute__((ext_vector_type(4))) float floatx4;

#define MFMA16(a,b,c) __builtin_amdgcn_mfma_f32_16x16x32_bf16(a,b,c,0,0,0)

// ---- workspace layout (bytes) ----
static constexpr size_t WS_SUM    = 0;          // 128 f32
static constexpr size_t WS_SQ     = 512;        // 128 f32
static constexpr size_t WS_FLAG   = 1024;       // u32 (1 = mask is 1-byte bools)
static constexpr size_t WS_HIST   = 1088;       // 13 u32 degree histogram
static constexpr size_t WS_OFF    = 1216;       // 13 u32 bucket offsets
static constexpr size_t WS_WHH    = 4096;       // 49152 u16, chunked frag layout
static constexpr size_t WS_WIH    = 102400;     // 49152 u16
static constexpr size_t WS_WSELF  = 200704;     // 16384 u16
static constexpr size_t WS_WNEIGH = 233472;     // 16384 u16
static constexpr size_t WS_DEG    = 266240;     // N u8
static constexpr size_t WS_PERM   = 466240;     // N i32
static constexpr size_t WS_XB     = 1266240;    // N*128 u16 (bf16 x)
static constexpr size_t WS_GI     = 52466240;   // N*384 u16 (bf16 gi)
// end = 206,066,240 bytes

__device__ __forceinline__ uint16_t f2b(float f){
    uint32_t u = __builtin_bit_cast(uint32_t, f);
    uint32_t r = u + 0x7FFFu + ((u >> 16) & 1u);
    return (uint16_t)(r >> 16);
}
__device__ __forceinline__ float b2f(uint16_t h){
    uint32_t u = ((uint32_t)h) << 16;
    return __builtin_bit_cast(float, u);
}
__device__ __forceinline__ float sigm(float x){
    float e = __builtin_amdgcn_exp2f(x * -1.4426950408889634f);
    return __builtin_amdgcn_rcpf(1.0f + e);
}
__device__ __forceinline__ float tanh_(float x){
    float e = __builtin_amdgcn_exp2f(x * 2.8853900817779268f); // e^{2x}
    return 1.0f - 2.0f * __builtin_amdgcn_rcpf(1.0f + e);
}

// ---- K0: zero BN accumulators + hist ----
__global__ void k_init(float* __restrict__ ws){
    ws[threadIdx.x] = 0.0f;
    ws[threadIdx.x + 256] = 0.0f;   // covers sum[128], sq[128], flag, hist, off
}

// ---- K1: detect mask element size (1-byte bool vs int32) ----
__global__ void k_detect(const uint32_t* __restrict__ mask_w, uint32_t* __restrict__ flag){
    __shared__ uint32_t any;
    if (threadIdx.x == 0) any = 0;
    __syncthreads();
    uint32_t loc = 0;
    for (int i = threadIdx.x; i < 4096; i += 256) loc |= (mask_w[i] & 0xFFFFFF00u);
    if (loc) atomicOr(&any, 1u);
    __syncthreads();
    if (threadIdx.x == 0) *flag = (any != 0) ? 1u : 0u;
}

// ---- K2: BN column stats ----
__global__ void k_stats(const float* __restrict__ feat, float* __restrict__ wsum, float* __restrict__ wsq){
    __shared__ float ssum[256], ssq[256];
    const int col = threadIdx.x & 127, half = threadIdx.x >> 7;
    float s = 0.f, q = 0.f;
    for (int r = blockIdx.x * 2 + half; r < NN; r += gridDim.x * 2){
        float v = feat[(size_t)r * DD + col];
        s += v; q += v * v;
    }
    ssum[threadIdx.x] = s; ssq[threadIdx.x] = q;
    __syncthreads();
    if (threadIdx.x < 128){
        atomicAdd(&wsum[col], ssum[threadIdx.x] + ssum[threadIdx.x + 128]);
        atomicAdd(&wsq[col],  ssq[threadIdx.x]  + ssq[threadIdx.x + 128]);
    }
}

// ---- K3: weights -> bf16 in MFMA-B-fragment-chunked layout ----
__global__ void k_prep(const float* __restrict__ Wih, const float* __restrict__ Whh,
                       const float* __restrict__ Wself, const float* __restrict__ Wneigh,
                       uint16_t* __restrict__ whh_c, uint16_t* __restrict__ wih_c,
                       uint16_t* __restrict__ wself_c, uint16_t* __restrict__ wneigh_c){
    int i = blockIdx.x * 256 + threadIdx.x;
    if (i < 49152){
        int j = i & 7, cidx = i >> 3, n = cidx % 384, kq = cidx / 384;
        whh_c[i] = f2b(Whh[n * 128 + kq * 8 + j]);
    } else if (i < 98304){
        int e = i - 49152;
        int j = e & 7, cidx = e >> 3, n = cidx % 384, kq = cidx / 384;
        wih_c[e] = f2b(Wih[n * 128 + kq * 8 + j]);
    } else if (i < 114688){
        int e = i - 98304;
        int j = e & 7, cidx = e >> 3, n = cidx & 127, kq = cidx >> 7;
        wself_c[e] = f2b(Wself[n * 128 + kq * 8 + j]);
    } else {
        int e = i - 114688;
        int j = e & 7, cidx = e >> 3, n = cidx & 127, kq = cidx >> 7;
        wneigh_c[e] = f2b(Wneigh[n * 128 + kq * 8 + j]);
    }
}

// ---- K4: per-node degree + histogram (LDS-aggregated; grid-stride) ----
// R2 post-mortem: per-thread global atomics onto 13 counters serialized at
// ~40ns/op -> 595us. LDS aggregation: <=13 global atomics per block.
__global__ void k_hist(const void* __restrict__ mask, const uint32_t* __restrict__ flag,
                       uint8_t* __restrict__ deg, uint32_t* __restrict__ hist){
    __shared__ uint32_t lh[13];
    if (threadIdx.x < 13) lh[threadIdx.x] = 0;
    __syncthreads();
    const uint32_t flg = *flag;
    for (int n = blockIdx.x * 256 + threadIdx.x; n < NN; n += gridDim.x * 256){
        int d = 0;
        if (flg){
            const uint8_t* m = (const uint8_t*)mask + (size_t)n * 12;
            for (int t = 0; t < 12; t++) d += m[t] ? 1 : 0;
        } else {
            const int* m = (const int*)mask + (size_t)n * 12;
            for (int t = 0; t < 12; t++) d += m[t] ? 1 : 0;
        }
        deg[n] = (uint8_t)d;
        atomicAdd(&lh[d], 1u);
    }
    __syncthreads();
    if (threadIdx.x < 13 && lh[threadIdx.x]) atomicAdd(&hist[threadIdx.x], lh[threadIdx.x]);
}

// ---- K5: bucket offsets (descending degree) ----
__global__ void k_scan(const uint32_t* __restrict__ hist, uint32_t* __restrict__ off){
    if (threadIdx.x == 0){
        uint32_t acc = 0;
        for (int d = 12; d >= 0; d--){ off[d] = acc; acc += hist[d]; }
    }
}

// ---- K6: scatter node ids into perm, block-aggregated atomics ----
__global__ void k_scatter(const uint8_t* __restrict__ deg, uint32_t* __restrict__ off,
                          int* __restrict__ perm){
    __shared__ uint32_t lh[13], basebuf[13];
    if (threadIdx.x < 13) lh[threadIdx.x] = 0;
    __syncthreads();
    int n = blockIdx.x * 256 + threadIdx.x;
    int d = 0; uint32_t r = 0;
    bool valid = n < NN;
    if (valid){ d = deg[n]; r = atomicAdd(&lh[d], 1u); }
    __syncthreads();
    if (threadIdx.x < 13 && lh[threadIdx.x]) basebuf[threadIdx.x] = atomicAdd(&off[threadIdx.x], lh[threadIdx.x]);
    __syncthreads();
    if (valid) perm[basebuf[d] + r] = n;
}

// ---- K7: BN apply -> x bf16 ----
__global__ void k_bn(const float* __restrict__ feat, const float* __restrict__ gamma,
                     const float* __restrict__ beta, const float* __restrict__ wsum,
                     const float* __restrict__ wsq, uint16_t* __restrict__ xb){
    const int col = threadIdx.x & 127;
    const int strideRows = (gridDim.x * blockDim.x) >> 7;
    const int row0 = (blockIdx.x * blockDim.x + threadIdx.x) >> 7;
    float mu  = wsum[col] * (1.0f / NN);
    float var = wsq[col] * (1.0f / NN) - mu * mu;
    float rs  = rsqrtf(var + 1e-5f);
    float g = gamma[col] * rs;
    float b = beta[col] - mu * g;
    for (int r = row0; r < NN; r += strideRows)
        xb[(size_t)r * DD + col] = f2b(feat[(size_t)r * DD + col] * g + b);
}

// ---- K8: gi = x @ W_ih^T + b_ih  (64 rows per wave, B reused 4x) ----
__global__ __launch_bounds__(256) void k_gi(const uint16_t* __restrict__ xb,
                                            const uint16_t* __restrict__ wih_c,
                                            const float* __restrict__ b_ih,
                                            uint16_t* __restrict__ gi){
    const int tid = threadIdx.x, lane = tid & 63, w = tid >> 6, q = lane >> 4, c = lane & 15;
    const int wrow = (blockIdx.x * 4 + w) * 64;
    if (wrow >= NN) return;
    short8 A[4][4];
#pragma unroll
    for (int m = 0; m < 4; m++)
#pragma unroll
        for (int kb = 0; kb < 4; kb++)
            A[m][kb] = *(const short8*)(xb + (size_t)(wrow + m * 16 + c) * 128 + kb * 32 + q * 8);
#pragma unroll
    for (int nb = 0; nb < 24; nb++){
        floatx4 acc[4];
#pragma unroll
        for (int m = 0; m < 4; m++) acc[m] = floatx4{0.f, 0.f, 0.f, 0.f};
#pragma unroll
        for (int kb = 0; kb < 4; kb++){
            short8 B = *(const short8*)(wih_c + ((size_t)(kb * 4 + q) * 384 + nb * 16 + c) * 8);
#pragma unroll
            for (int m = 0; m < 4; m++) acc[m] = MFMA16(A[m][kb], B, acc[m]);
        }
        int colg = nb * 16 + c;
        float bias = b_ih[colg];
#pragma unroll
        for (int m = 0; m < 4; m++)
#pragma unroll
            for (int j = 0; j < 4; j++){
                int row = wrow + m * 16 + q * 4 + j;
                gi[(size_t)row * 384 + colg] = f2b(acc[m][j] + bias);
            }
    }
}

// ---- K9: GRU scan (degree-sorted) + final projections ----
__global__ __launch_bounds__(256, 1) void k_gru(
    const uint16_t* __restrict__ xb, const uint16_t* __restrict__ gi,
    const uint16_t* __restrict__ whh_c, const uint16_t* __restrict__ wself_c,
    const uint16_t* __restrict__ wneigh_c, const float* __restrict__ b_hh,
    const int* __restrict__ src_idx, const void* __restrict__ mask,
    const uint32_t* __restrict__ flag, const int* __restrict__ perm,
    const uint8_t* __restrict__ degp, float* __restrict__ out)
{
    __shared__ __align__(16) uint16_t hbuf[2][64][136];
    __shared__ int src_s[768];
    __shared__ uint8_t mask_s[768];
    __shared__ int perm_s[64];
    __shared__ int tmax_s;

    const int tid = threadIdx.x, lane = tid & 63, w = tid >> 6, q = lane >> 4, c = lane & 15;
    const int base = blockIdx.x * 64;

    if (tid < 64) perm_s[tid] = perm[base + tid];
    if (tid == 0) tmax_s = 0;
    __syncthreads();

    const uint32_t flg = *flag;
    for (int i = tid; i < 768; i += 256){
        int node = perm_s[i / 12];
        size_t offn = (size_t)node * 12 + (i % 12);
        src_s[i] = src_idx[offn];
        uint8_t mv;
        if (flg) mv = ((const uint8_t*)mask)[offn] ? 1 : 0;
        else     mv = ((const int*)mask)[offn] ? 1 : 0;
        mask_s[i] = mv;
    }
    if (tid < 64) atomicMax(&tmax_s, (int)degp[perm_s[tid]]);
    for (int i = tid; i < 64 * 136 / 2; i += 256) ((uint32_t*)hbuf[0])[i] = 0;

    // persistent W_hh B fragments (96 VGPRs) + biases
    short8 Bh[3][2][4];
    float bhh[3][2];
#pragma unroll
    for (int g = 0; g < 3; g++)
#pragma unroll
        for (int p = 0; p < 2; p++){
            int n = g * 128 + w * 32 + p * 16 + c;
            bhh[g][p] = b_hh[n];
#pragma unroll
            for (int kb = 0; kb < 4; kb++)
                Bh[g][p][kb] = *(const short8*)(whh_c + ((size_t)(kb * 4 + q) * 384 + n) * 8);
        }

    float hC[4][2][4];
#pragma unroll
    for (int m = 0; m < 4; m++)
#pragma unroll
        for (int p = 0; p < 2; p++)
#pragma unroll
            for (int j = 0; j < 4; j++) hC[m][p][j] = 0.f;

    __syncthreads();
    const int tmax = tmax_s;

    for (int t = 0; t < tmax; t++){
        const int rb = t & 1, wbuf = rb ^ 1;
        // gather gi for this step: 1 base addr per (m,j), 6 imm-offset loads
        uint16_t gv[4][3][2][4];
        uint8_t  mk[4][4];
#pragma unroll
        for (int m = 0; m < 4; m++)
#pragma unroll
            for (int j = 0; j < 4; j++){
                int row = m * 16 + q * 4 + j;
                int s = src_s[row * 12 + t];
                mk[m][j] = mask_s[row * 12 + t];
                const uint16_t* a = gi + (size_t)s * 384 + w * 32 + c;
                gv[m][0][0][j] = a[0];   gv[m][0][1][j] = a[16];
                gv[m][1][0][j] = a[128]; gv[m][1][1][j] = a[144];
                gv[m][2][0][j] = a[256]; gv[m][2][1][j] = a[272];
            }
#pragma unroll
        for (int m = 0; m < 4; m++){
            short8 A[4];
#pragma unroll
            for (int kb = 0; kb < 4; kb++)
                A[kb] = *(const short8*)&hbuf[rb][m * 16 + c][kb * 32 + q * 8];
            floatx4 acc[3][2];
#pragma unroll
            for (int g = 0; g < 3; g++)
#pragma unroll
                for (int p = 0; p < 2; p++){
                    floatx4 a0 = {0.f, 0.f, 0.f, 0.f};
#pragma unroll
                    for (int kb = 0; kb < 4; kb++) a0 = MFMA16(A[kb], Bh[g][p][kb], a0);
                    acc[g][p] = a0;
                }
#pragma unroll
            for (int p = 0; p < 2; p++)
#pragma unroll
                for (int j = 0; j < 4; j++){
                    float grv = b2f(gv[m][0][p][j]) + acc[0][p][j] + bhh[0][p];
                    float gzv = b2f(gv[m][1][p][j]) + acc[1][p][j] + bhh[1][p];
                    float hn  = acc[2][p][j] + bhh[2][p];
                    float r = sigm(grv);
                    float z = sigm(gzv);
                    float nn = tanh_(b2f(gv[m][2][p][j]) + r * hn);
                    float hold = hC[m][p][j];
                    float hnew = nn + z * (hold - nn);
                    hnew = mk[m][j] ? hnew : hold;
                    hC[m][p][j] = hnew;
                    hbuf[wbuf][m * 16 + q * 4 + j][w * 32 + p * 16 + c] = f2b(hnew);
                }
        }
        __syncthreads();
    }

    const int fb = tmax & 1;   // final h buffer

    // epilogue: out = x @ W_self^T + h @ W_neigh^T
    floatx4 acc2[4][2];
#pragma unroll
    for (int m = 0; m < 4; m++)
#pragma unroll
        for (int p = 0; p < 2; p++) acc2[m][p] = floatx4{0.f, 0.f, 0.f, 0.f};
#pragma unroll
    for (int m = 0; m < 4; m++){
        short8 A[4];
#pragma unroll
        for (int kb = 0; kb < 4; kb++)
            A[kb] = *(const short8*)&hbuf[fb][m * 16 + c][kb * 32 + q * 8];
#pragma unroll
        for (int p = 0; p < 2; p++)
#pragma unroll
            for (int kb = 0; kb < 4; kb++){
                short8 B = *(const short8*)(wneigh_c + ((size_t)(kb * 4 + q) * 128 + w * 32 + p * 16 + c) * 8);
                acc2[m][p] = MFMA16(A[kb], B, acc2[m][p]);
            }
    }
#pragma unroll
    for (int m = 0; m < 4; m++){
        int xrow = perm_s[m * 16 + c];
        short8 A[4];
#pragma unroll
        for (int kb = 0; kb < 4; kb++)
            A[kb] = *(const short8*)(xb + (size_t)xrow * 128 + kb * 32 + q * 8);
#pragma unroll
        for (int p = 0; p < 2; p++)
#pragma unroll
            for (int kb = 0; kb < 4; kb++){
                short8 B = *(const short8*)(wself_c + ((size_t)(kb * 4 + q) * 128 + w * 32 + p * 16 + c) * 8);
                acc2[m][p] = MFMA16(A[kb], B, acc2[m][p]);
            }
    }
#pragma unroll
    for (int m = 0; m < 4; m++){
#pragma unroll
        for (int j = 0; j < 4; j++){
            int orow = perm_s[m * 16 + q * 4 + j];
#pragma unroll
            for (int p = 0; p < 2; p++)
                out[(size_t)orow * 128 + w * 32 + p * 16 + c] = acc2[m][p][j];
        }
    }
}

extern "C" void kernel_launch(void* const* d_in, const int* in_sizes, int n_in,
                              void* d_out, int out_size, void* d_ws, size_t ws_size,
                              hipStream_t stream) {
    const float* feat    = (const float*)d_in[0];
    const float* gamma   = (const float*)d_in[1];
    const float* beta    = (const float*)d_in[2];
    const float* W_ih    = (const float*)d_in[3];
    const float* W_hh    = (const float*)d_in[4];
    const float* b_ih    = (const float*)d_in[5];
    const float* b_hh    = (const float*)d_in[6];
    const float* W_self  = (const float*)d_in[7];
    const float* W_neigh = (const float*)d_in[8];
    const int*   src_idx = (const int*)d_in[9];
    const void*  mask    = (const void*)d_in[10];
    float* out = (float*)d_out;

    char* ws = (char*)d_ws;
    float*    wsum     = (float*)(ws + WS_SUM);
    float*    wsq      = (float*)(ws + WS_SQ);
    uint32_t* flag     = (uint32_t*)(ws + WS_FLAG);
    uint32_t* hist     = (uint32_t*)(ws + WS_HIST);
    uint32_t* off      = (uint32_t*)(ws + WS_OFF);
    uint16_t* whh_c    = (uint16_t*)(ws + WS_WHH);
    uint16_t* wih_c    = (uint16_t*)(ws + WS_WIH);
    uint16_t* wself_c  = (uint16_t*)(ws + WS_WSELF);
    uint16_t* wneigh_c = (uint16_t*)(ws + WS_WNEIGH);
    uint8_t*  deg      = (uint8_t*)(ws + WS_DEG);
    int*      perm     = (int*)(ws + WS_PERM);
    uint16_t* xb       = (uint16_t*)(ws + WS_XB);
    uint16_t* gi       = (uint16_t*)(ws + WS_GI);

    k_init   <<<1,    256, 0, stream>>>((float*)ws);
    k_detect <<<1,    256, 0, stream>>>((const uint32_t*)mask, flag);
    k_stats  <<<512,  256, 0, stream>>>(feat, wsum, wsq);
    k_prep   <<<512,  256, 0, stream>>>(W_ih, W_hh, W_self, W_neigh, whh_c, wih_c, wself_c, wneigh_c);
    k_hist   <<<256,  256, 0, stream>>>(mask, flag, deg, hist);
    k_scan   <<<1,    64,  0, stream>>>(hist, off);
    k_scatter<<<782,  256, 0, stream>>>(deg, off, perm);
    k_bn     <<<782,  256, 0, stream>>>(feat, gamma, beta, wsum, wsq, xb);
    k_gi     <<<782,  256, 0, stream>>>(xb, wih_c, b_ih, gi);
    k_gru    <<<3125, 256, 0, stream>>>(xb, gi, whh_c, wself_c, wneigh_c, b_hh, src_idx, mask, flag, perm, deg, out);
}